// Round 7
// baseline (2518.222 us; speedup 1.0000x reference)
//
#include <hip/hip_runtime.h>

typedef _Float16 half8 __attribute__((ext_vector_type(8)));
typedef float float4v __attribute__((ext_vector_type(4)));
typedef unsigned short u16;
typedef unsigned short ushort8 __attribute__((ext_vector_type(8)));
typedef unsigned int u32;
typedef unsigned long long u64;

// ---------- workspace layout (bytes); total ~1.06 MB ----------
// hxF: FAST tagged packets (plain stores -> per-XCD L2; sc0 loads).
// hxS: SLOW copy (agent scope -> LLC) -- correctness net for cross-XCD placement.
// Packet: low 16b hi-f16, next 16b lo-f16 (writer pre-split), high 32b tag=ti+1.
// 2(slot)*2(d)*4(g)*8(q8)*16(row)*32(unit) packets * 8B = 524288 B each copy.
#define OFF_HXF   ((size_t)0)
#define OFF_HXS   ((size_t)524288)
#define OFF_FLAGF ((size_t)1048576)   /* 64 flags x 16-int spacing = 4096 B */
#define OFF_FLAGS ((size_t)1052672)   /* 4096 B */
#define OFF_MASK  ((size_t)1056768)   /* 32768 B */

#define LO_SCALE   2048.0f
#define LO_ISCALE  (1.0f / 2048.0f)

__device__ __forceinline__ u16 h2u(_Float16 h) {
  union { _Float16 h; u16 u; } u; u.h = h; return u.u;
}
__device__ __forceinline__ float ftanh(float x) {
  float e = __expf(x + x);
  return 1.0f - 2.0f * __builtin_amdgcn_rcpf(e + 1.0f);
}
__device__ __forceinline__ float clamp30(float v) {
  return fminf(30.0f, fmaxf(-30.0f, v));
}
// split v = hi + lo/2048 (lo pre-scaled so it never hits f16 subnormals)
__device__ __forceinline__ void split2(float v, _Float16& hi, _Float16& lo) {
  hi = (_Float16)v;
  lo = (_Float16)((v - (float)hi) * LO_SCALE);
}

// sc0 loads: bypass L1, served by this XCD's L2 (fast, XCD-coherent path).
__device__ __forceinline__ u32 ld_l2_u32(const u32* p) {
  u32 r;
  asm volatile("global_load_dword %0, %1, off sc0\n\ts_waitcnt vmcnt(0)"
               : "=&v"(r) : "v"(p) : "memory");
  return r;
}
__device__ __forceinline__ u64 ld_l2_u64(const u64* p) {
  u64 r;
  asm volatile("global_load_dwordx2 %0, %1, off sc0\n\ts_waitcnt vmcnt(0)"
               : "=&v"(r) : "v"(p) : "memory");
  return r;
}
__device__ __forceinline__ void ld16_l2(const u64* p, u64* v) {
  asm volatile(
      "global_load_dwordx2 %0, %16, off sc0\n\t"
      "global_load_dwordx2 %1, %16, off offset:8 sc0\n\t"
      "global_load_dwordx2 %2, %16, off offset:16 sc0\n\t"
      "global_load_dwordx2 %3, %16, off offset:24 sc0\n\t"
      "global_load_dwordx2 %4, %16, off offset:32 sc0\n\t"
      "global_load_dwordx2 %5, %16, off offset:40 sc0\n\t"
      "global_load_dwordx2 %6, %16, off offset:48 sc0\n\t"
      "global_load_dwordx2 %7, %16, off offset:56 sc0\n\t"
      "global_load_dwordx2 %8, %16, off offset:64 sc0\n\t"
      "global_load_dwordx2 %9, %16, off offset:72 sc0\n\t"
      "global_load_dwordx2 %10, %16, off offset:80 sc0\n\t"
      "global_load_dwordx2 %11, %16, off offset:88 sc0\n\t"
      "global_load_dwordx2 %12, %16, off offset:96 sc0\n\t"
      "global_load_dwordx2 %13, %16, off offset:104 sc0\n\t"
      "global_load_dwordx2 %14, %16, off offset:112 sc0\n\t"
      "global_load_dwordx2 %15, %16, off offset:120 sc0\n\t"
      "s_waitcnt vmcnt(0)"
      : "=&v"(v[0]), "=&v"(v[1]), "=&v"(v[2]), "=&v"(v[3]),
        "=&v"(v[4]), "=&v"(v[5]), "=&v"(v[6]), "=&v"(v[7]),
        "=&v"(v[8]), "=&v"(v[9]), "=&v"(v[10]), "=&v"(v[11]),
        "=&v"(v[12]), "=&v"(v[13]), "=&v"(v[14]), "=&v"(v[15])
      : "v"(p)
      : "memory");
}

// ---------------- mask[t][b] = any(x[b,t,:] != 0); zero hx (both copies) + flags ----------------
// Plain zero-stores are fine: end-of-dispatch release makes them LLC-visible
// before k_scan starts; k_scan's first sc0/agent reads then pull fresh zeros.
__global__ __launch_bounds__(256) void k_mask(const float* __restrict__ x,
                                              unsigned char* __restrict__ mask,
                                              u64* __restrict__ hxAll,
                                              int* __restrict__ flagAll) {
  if (blockIdx.x < 512) hxAll[(size_t)blockIdx.x * 256 + threadIdx.x] = 0ull;
  if (blockIdx.x < 8) flagAll[blockIdx.x * 256 + threadIdx.x] = 0;
  int w = threadIdx.x >> 6, l = threadIdx.x & 63;
  int row = blockIdx.x * 4 + w;  // row = b*512 + t, 0..32767
  const float4v* p = (const float4v*)(x + (size_t)row * 256 + l * 4);
  float4v v = *p;
  int nz = (v[0] != 0.f) || (v[1] != 0.f) || (v[2] != 0.f) || (v[3] != 0.f);
  unsigned long long bal = __ballot(nz);
  if (l == 0) {
    int b = row >> 9, t = row & 511;
    mask[t * 64 + b] = (bal != 0ull) ? 1 : 0;
  }
}

// ---------------- fused sequential scan, split-f16 (fp32-grade), fp32 out ----------------
// Same-XCD L2 exchange with agent-scope safety net:
//  - bid = q8*8 + sg places all 8 octant-WGs of a scan group on one XCD under
//    round-robin dispatch (bid%8). Their shared L2 is coherent: writer's plain
//    stores land dirty in L2; readers' sc0 loads (L1-bypass) see them in
//    ~200cy -- 3-4x cheaper than the agent/LLC path every prior round used.
//  - Placement is NOT guaranteed, so correctness never depends on it:
//    (a) 8B tagged packets (tag can't tear from payload; staleness -- incl. a
//        permanently-stale cross-XCD L2 line -- is detected and retried);
//    (b) writers dual-publish packets+flag to an agent-scope LLC copy;
//    (c) readers watchdog the fast path (128 stale polls or 64 stale data
//        rounds while the LLC copy is fresh) and permanently fall back to the
//        agent path for that partner. Deadlock-free under any placement.
//  - No drains, no B4: overwrite safety is pure tag induction (writer reaches
//    D(ti+2), overwriting slot ti&1, only after B(ti+2) validated partner tags
//    >= ti+2, i.e. partners' B2(ti+1) barrier drained their reads of that
//    slot). Field-validated 2-barrier structure (r4/r5/r6 all passed).
__global__ __launch_bounds__(256, 1) void k_scan(const float* __restrict__ Wk_f,
                                                 const float* __restrict__ Wr_f,
                                                 const float* __restrict__ b_f,
                                                 const float* __restrict__ Wk_b,
                                                 const float* __restrict__ Wr_b,
                                                 const float* __restrict__ b_b,
                                                 const float* __restrict__ x,
                                                 const unsigned char* __restrict__ mask,
                                                 u64* __restrict__ hxF,
                                                 u64* __restrict__ hxS,
                                                 int* __restrict__ flagF,
                                                 int* __restrict__ flagS,
                                                 float* __restrict__ out) {
  __shared__ u16 hhi[16][264], hlo[16][264];       // f16 bits, full 256 units
  __shared__ u16 xhi[2][16][264], xlo[2][16][264]; // f16 x tile, double-buffered
  __shared__ float zb[4][16][34];                  // [gate][row][unitcol+pad]

  int bid = blockIdx.x;
  int sg = bid & 7, q8 = bid >> 3;
  int d = sg >> 2, g = sg & 3;
  int tid = threadIdx.x;
  int w = tid >> 6, l = tid & 63;
  int p = w >> 1, sl = w & 1;
  int lg = l >> 4, li = l & 15;
  const float* Wk = d ? Wk_b : Wk_f;
  const float* Wr = d ? Wr_b : Wr_f;
  const float* bias = d ? b_b : b_f;

  int ncol0 = 256 * (2 * p) + 32 * q8 + 16 * sl + li;  // gate 2p column
  int ncol1 = ncol0 + 256;                             // gate 2p+1

  // Register-resident split weight B-fragments (m92-verified addressing).
  half8 wkh[2][8], wkl[2][8], wrh[2][8], wrl[2][8];
#pragma unroll
  for (int kk = 0; kk < 8; ++kk) {
#pragma unroll
    for (int jj = 0; jj < 8; ++jj) {
      int k = 32 * kk + 8 * lg + jj;
      _Float16 hi, lo;
      split2(Wk[(size_t)k * 1024 + ncol0], hi, lo); wkh[0][kk][jj] = hi; wkl[0][kk][jj] = lo;
      split2(Wk[(size_t)k * 1024 + ncol1], hi, lo); wkh[1][kk][jj] = hi; wkl[1][kk][jj] = lo;
      split2(Wr[(size_t)k * 1024 + ncol0], hi, lo); wrh[0][kk][jj] = hi; wrl[0][kk][jj] = lo;
      split2(Wr[(size_t)k * 1024 + ncol1], hi, lo); wrh[1][kk][jj] = hi; wrl[1][kk][jj] = lo;
    }
  }
  float bs0 = bias[ncol0], bs1 = bias[ncol1];

  for (int i = tid; i < 16 * 264; i += 256) { ((u16*)hhi)[i] = 0; ((u16*)hlo)[i] = 0; }
  float cst[2] = {0.f, 0.f}, hst[2] = {0.f, 0.f};
  int fl_self = (sg * 8 + q8) * 16;
  bool slowp = false;  // per-thread permanent fallback to agent/LLC path

  // x staging: thread covers row sr, 16 cols at c0 of the 16x256 fp32 tile
  int sr = tid >> 4, c0 = (tid & 15) * 16;
  const float* xrow = x + ((size_t)(16 * g + sr) * 512) * 256 + c0;
  {
    int t0 = d ? 511 : 0;
    const float4v* xp = (const float4v*)(xrow + (size_t)t0 * 256);
    float va[16];
    *(float4v*)&va[0] = xp[0]; *(float4v*)&va[4] = xp[1];
    *(float4v*)&va[8] = xp[2]; *(float4v*)&va[12] = xp[3];
    half8 h0, h1, l0, l1;
#pragma unroll
    for (int j = 0; j < 8; ++j) {
      _Float16 hi, lo;
      split2(va[j], hi, lo);     h0[j] = hi; l0[j] = lo;
      split2(va[8 + j], hi, lo); h1[j] = hi; l1[j] = lo;
    }
    *(half8*)(void*)&xhi[0][sr][c0] = h0; *(half8*)(void*)&xhi[0][sr][c0 + 8] = h1;
    *(half8*)(void*)&xlo[0][sr][c0] = l0; *(half8*)(void*)&xlo[0][sr][c0 + 8] = l1;
  }
  __syncthreads();

  for (int ti = 0; ti < 512; ++ti) {
    int t = d ? (511 - ti) : ti;
    int buf = ti & 1;

    // issue next step's x loads + this step's mask loads early
    float4v xa0, xa1, xa2, xa3;
    if (ti < 511) {
      int tn = d ? (510 - ti) : (ti + 1);
      const float4v* xp = (const float4v*)(xrow + (size_t)tn * 256);
      xa0 = xp[0]; xa1 = xp[1]; xa2 = xp[2]; xa3 = xp[3];
    }
    int m0 = 2 * (tid >> 5);
    int mk0 = mask[t * 64 + 16 * g + m0];
    int mk1 = mask[t * 64 + 16 * g + m0 + 1];

    // phase A: z = b + x@Wk (split); covers partner publish->visibility window
    float4v zm0 = {bs0, bs0, bs0, bs0}, zm1 = {bs1, bs1, bs1, bs1};
    float4v zc0 = {0.f, 0.f, 0.f, 0.f}, zc1 = {0.f, 0.f, 0.f, 0.f};
#pragma unroll
    for (int kk = 0; kk < 8; ++kk) {
      half8 axh = *(const half8*)(const void*)&xhi[buf][li][32 * kk + 8 * lg];
      half8 axl = *(const half8*)(const void*)&xlo[buf][li][32 * kk + 8 * lg];
      zm0 = __builtin_amdgcn_mfma_f32_16x16x32_f16(axh, wkh[0][kk], zm0, 0, 0, 0);
      zc0 = __builtin_amdgcn_mfma_f32_16x16x32_f16(axh, wkl[0][kk], zc0, 0, 0, 0);
      zc0 = __builtin_amdgcn_mfma_f32_16x16x32_f16(axl, wkh[0][kk], zc0, 0, 0, 0);
      zm1 = __builtin_amdgcn_mfma_f32_16x16x32_f16(axh, wkh[1][kk], zm1, 0, 0, 0);
      zc1 = __builtin_amdgcn_mfma_f32_16x16x32_f16(axh, wkl[1][kk], zc1, 0, 0, 0);
      zc1 = __builtin_amdgcn_mfma_f32_16x16x32_f16(axl, wkh[1][kk], zc1, 0, 0, 0);
    }

    // phase B: fast L2 spin -> one-shot 16-packet sc0 load -> tag validation,
    // with watchdog fallback to the agent/LLC copy (placement-independent).
    if (ti > 0 && tid < 224) {
      int pi = tid >> 5, rb = tid & 31;
      int qq = (q8 + 1 + pi) & 7;
      int rm = rb >> 1, cc = 16 * (rb & 1);
      int slot2 = (ti - 1) & 1;
      size_t pidx = ((((size_t)(slot2 * 2 + d) * 4 + g) * 8 + qq) * 16 + rm) * 32 + cc;
      const int* fS = flagS + (sg * 8 + qq) * 16;
      u64 v[16];
      if (!slowp) {
        const u32* fF = (const u32*)(const void*)(flagF + (sg * 8 + qq) * 16);
        int spins = 0;
        for (;;) {
          if ((int)ld_l2_u32(fF) >= ti) break;
          if (++spins >= 128) {
            spins = 0;
            if (__hip_atomic_load(fS, __ATOMIC_RELAXED, __HIP_MEMORY_SCOPE_AGENT) >= ti) {
              slowp = true; break;  // LLC fresh but L2 stale => cross-XCD
            }
          }
          __builtin_amdgcn_s_sleep(1);
        }
        if (!slowp) {
          ld16_l2(hxF + pidx, v);
          int rounds = 0;
          for (;;) {
            u32 bad = 0;
#pragma unroll
            for (int j = 0; j < 16; ++j)
              if ((u32)(v[j] >> 32) < (u32)ti) bad |= (1u << j);
            if (!bad) break;
            if (++rounds > 64) { slowp = true; break; }  // stale L2 data line
            __builtin_amdgcn_s_sleep(1);
#pragma unroll
            for (int j = 0; j < 16; ++j)
              if (bad & (1u << j)) v[j] = ld_l2_u64(hxF + pidx + j);
          }
        }
      }
      if (slowp) {  // agent/LLC path (r6 protocol; correctness-proven)
        while (__hip_atomic_load(fS, __ATOMIC_RELAXED, __HIP_MEMORY_SCOPE_AGENT) < ti)
          __builtin_amdgcn_s_sleep(1);
#pragma unroll
        for (int j = 0; j < 16; ++j)
          v[j] = __hip_atomic_load(hxS + pidx + j, __ATOMIC_RELAXED, __HIP_MEMORY_SCOPE_AGENT);
        for (;;) {
          u32 bad = 0;
#pragma unroll
          for (int j = 0; j < 16; ++j)
            if ((u32)(v[j] >> 32) < (u32)ti) bad |= (1u << j);
          if (!bad) break;
          __builtin_amdgcn_s_sleep(1);
#pragma unroll
          for (int j = 0; j < 16; ++j)
            if (bad & (1u << j))
              v[j] = __hip_atomic_load(hxS + pidx + j, __ATOMIC_RELAXED, __HIP_MEMORY_SCOPE_AGENT);
        }
      }
      // unpack: payload is the writer's split pair (no reader-side split2)
      ushort8 h0, h1, l0, l1;
#pragma unroll
      for (int j = 0; j < 8; ++j) {
        u32 d0 = (u32)v[j], d1 = (u32)v[8 + j];
        h0[j] = (u16)(d0 & 0xffffu); l0[j] = (u16)(d0 >> 16);
        h1[j] = (u16)(d1 & 0xffffu); l1[j] = (u16)(d1 >> 16);
      }
      *(ushort8*)(void*)&hhi[rm][32 * qq + cc]     = h0;
      *(ushort8*)(void*)&hhi[rm][32 * qq + cc + 8] = h1;
      *(ushort8*)(void*)&hlo[rm][32 * qq + cc]     = l0;
      *(ushort8*)(void*)&hlo[rm][32 * qq + cc + 8] = l1;
    }
    __syncthreads();  // B2: hhi/hlo complete (drains phase-B loads)

    // phase C: z += h @ Wr (split)
#pragma unroll
    for (int kk = 0; kk < 8; ++kk) {
      half8 ahh = *(const half8*)(const void*)&hhi[li][32 * kk + 8 * lg];
      half8 ahl = *(const half8*)(const void*)&hlo[li][32 * kk + 8 * lg];
      zm0 = __builtin_amdgcn_mfma_f32_16x16x32_f16(ahh, wrh[0][kk], zm0, 0, 0, 0);
      zc0 = __builtin_amdgcn_mfma_f32_16x16x32_f16(ahh, wrl[0][kk], zc0, 0, 0, 0);
      zc0 = __builtin_amdgcn_mfma_f32_16x16x32_f16(ahl, wrh[0][kk], zc0, 0, 0, 0);
      zm1 = __builtin_amdgcn_mfma_f32_16x16x32_f16(ahh, wrh[1][kk], zm1, 0, 0, 0);
      zc1 = __builtin_amdgcn_mfma_f32_16x16x32_f16(ahh, wrl[1][kk], zc1, 0, 0, 0);
      zc1 = __builtin_amdgcn_mfma_f32_16x16x32_f16(ahl, wrh[1][kk], zc1, 0, 0, 0);
    }
#pragma unroll
    for (int rr = 0; rr < 4; ++rr) {
      zb[2 * p][4 * lg + rr][16 * sl + li] = clamp30(zm0[rr] + zc0[rr] * LO_ISCALE);
      zb[2 * p + 1][4 * lg + rr][16 * sl + li] = clamp30(zm1[rr] + zc1[rr] * LO_ISCALE);
    }

    // stage x(t+1) into the other buffer (read next iter, after B3)
    if (ti < 511) {
      float va[16];
      *(float4v*)&va[0] = xa0; *(float4v*)&va[4] = xa1;
      *(float4v*)&va[8] = xa2; *(float4v*)&va[12] = xa3;
      half8 h0, h1, l0, l1;
#pragma unroll
      for (int j = 0; j < 8; ++j) {
        _Float16 hi, lo;
        split2(va[j], hi, lo);     h0[j] = hi; l0[j] = lo;
        split2(va[8 + j], hi, lo); h1[j] = hi; l1[j] = lo;
      }
      *(half8*)(void*)&xhi[buf ^ 1][sr][c0] = h0;
      *(half8*)(void*)&xhi[buf ^ 1][sr][c0 + 8] = h1;
      *(half8*)(void*)&xlo[buf ^ 1][sr][c0] = l0;
      *(half8*)(void*)&xlo[buf ^ 1][sr][c0 + 8] = l1;
    }
    __syncthreads();  // B3: zb + x stage ready

    // phase D: state update — thread owns unit-col uo, rows m0,m0+1.
    // Publish = dual packet stores (plain->L2 fast copy; agent->LLC slow copy)
    // + dual flag. No drain anywhere; tags carry all ordering.
    int uo = tid & 31;
    int slot = ti & 1;
    u64 tagw = ((u64)(u32)(ti + 1)) << 32;
#pragma unroll
    for (int e2 = 0; e2 < 2; ++e2) {
      int m = m0 + e2;
      float zi = zb[0][m][uo];
      float zf = zb[1][m][uo];
      float zg = zb[2][m][uo];
      float zo = zb[3][m][uo];
      float gi = ftanh(zi), gf = ftanh(zf), gg = ftanh(zg), go = ftanh(zo);
      float cn = gf * cst[e2] + gi * gg;
      float hn = go * ftanh(cn);
      bool mk = (e2 ? mk1 : mk0) != 0;
      cst[e2] = mk ? cn : cst[e2];
      hst[e2] = mk ? hn : hst[e2];
      float hv = hst[e2];
      _Float16 hi, lo; split2(hv, hi, lo);
      hhi[m][32 * q8 + uo] = h2u(hi);
      hlo[m][32 * q8 + uo] = h2u(lo);
      u64 pk = (u64)((u32)h2u(hi) | ((u32)h2u(lo) << 16)) | tagw;
      size_t didx = ((((size_t)(slot * 2 + d) * 4 + g) * 8 + q8) * 16 + m) * 32 + uo;
      __hip_atomic_store(hxF + didx, pk, __ATOMIC_RELAXED, __HIP_MEMORY_SCOPE_WORKGROUP);
      __hip_atomic_store(hxS + didx, pk, __ATOMIC_RELAXED, __HIP_MEMORY_SCOPE_AGENT);
    }
    if (tid == 0) {
      __hip_atomic_store(flagF + fl_self, ti + 1, __ATOMIC_RELAXED, __HIP_MEMORY_SCOPE_WORKGROUP);
      __hip_atomic_store(flagS + fl_self, ti + 1, __ATOMIC_RELAXED, __HIP_MEMORY_SCOPE_AGENT);
    }
    // out stores last: never gate the publication
#pragma unroll
    for (int e2 = 0; e2 < 2; ++e2) {
      int b = 16 * g + m0 + e2;
      out[((size_t)b * 512 + t) * 512 + 256 * d + 32 * q8 + uo] = hst[e2];
    }
  }

  // state_h (fp32)
  {
    int uo = tid & 31;
    int m0 = 2 * (tid >> 5);
#pragma unroll
    for (int e2 = 0; e2 < 2; ++e2) {
      int b = 16 * g + m0 + e2;
      out[(size_t)16777216 + (size_t)b * 512 + 256 * d + 32 * q8 + uo] = hst[e2];
    }
  }
}

extern "C" void kernel_launch(void* const* d_in, const int* in_sizes, int n_in,
                              void* d_out, int out_size, void* d_ws, size_t ws_size,
                              hipStream_t stream) {
  const float* x    = (const float*)d_in[0];
  const float* Wk_f = (const float*)d_in[1];
  const float* Wr_f = (const float*)d_in[2];
  const float* b_f  = (const float*)d_in[3];
  const float* Wk_b = (const float*)d_in[4];
  const float* Wr_b = (const float*)d_in[5];
  const float* b_b  = (const float*)d_in[6];
  char* ws = (char*)d_ws;
  u64* hxF   = (u64*)(ws + OFF_HXF);
  u64* hxS   = (u64*)(ws + OFF_HXS);
  int* flagF = (int*)(ws + OFF_FLAGF);
  int* flagS = (int*)(ws + OFF_FLAGS);
  unsigned char* maskp = (unsigned char*)(ws + OFF_MASK);
  float* out = (float*)d_out;

  k_mask<<<8192, 256, 0, stream>>>(x, maskp, hxF, flagF);
  k_scan<<<64, 256, 0, stream>>>(Wk_f, Wr_f, b_f, Wk_b, Wr_b, b_b, x, maskp,
                                 hxF, hxS, flagF, flagS, out);
}

// Round 8
// 2250.702 us; speedup vs baseline: 1.1189x; 1.1189x over previous
//
#include <hip/hip_runtime.h>

typedef _Float16 half8 __attribute__((ext_vector_type(8)));
typedef float float4v __attribute__((ext_vector_type(4)));
typedef unsigned short u16;
typedef unsigned short ushort8 __attribute__((ext_vector_type(8)));
typedef unsigned int u32;
typedef unsigned long long u64;

// ---------- workspace layout (bytes); total ~556 KB ----------
// hx: tagged 8B packets, one per (slot,d,g,q8,row16,unit32):
//   low 16b = hi f16, next 16b = lo f16 (writer pre-split), high 32b = tag (ti+1)
//   2*2*4*8*16*32 packets * 8B = 524288 B.  NO separate flags: packet 0 of each
//   (slot,d,g,q8) block is the SENTINEL readers poll.
#define OFF_HX    ((size_t)0)
#define OFF_MASK  ((size_t)524288)   /* 32768 B */

#define LO_SCALE   2048.0f
#define LO_ISCALE  (1.0f / 2048.0f)

__device__ __forceinline__ u16 h2u(_Float16 h) {
  union { _Float16 h; u16 u; } u; u.h = h; return u.u;
}
__device__ __forceinline__ float ftanh(float x) {
  // tanh(x) = 1 - 2/(exp(2x)+1); exact saturation for large |x|
  float e = __expf(x + x);
  return 1.0f - 2.0f * __builtin_amdgcn_rcpf(e + 1.0f);
}
__device__ __forceinline__ float clamp30(float v) {
  return fminf(30.0f, fmaxf(-30.0f, v));
}
// split v = hi + lo/2048 (lo pre-scaled so it never hits f16 subnormals)
__device__ __forceinline__ void split2(float v, _Float16& hi, _Float16& lo) {
  hi = (_Float16)v;
  lo = (_Float16)((v - (float)hi) * LO_SCALE);
}

// ---------------- mask[t][b] = any(x[b,t,:] != 0); also zero hx tags ----------------
__global__ __launch_bounds__(256) void k_mask(const float* __restrict__ x,
                                              unsigned char* __restrict__ mask,
                                              u64* __restrict__ hx64) {
  if (blockIdx.x < 256) hx64[(size_t)blockIdx.x * 256 + threadIdx.x] = 0ull;
  int w = threadIdx.x >> 6, l = threadIdx.x & 63;
  int row = blockIdx.x * 4 + w;  // row = b*512 + t, 0..32767
  const float4v* p = (const float4v*)(x + (size_t)row * 256 + l * 4);
  float4v v = *p;
  int nz = (v[0] != 0.f) || (v[1] != 0.f) || (v[2] != 0.f) || (v[3] != 0.f);
  unsigned long long bal = __ballot(nz);
  if (l == 0) {
    int b = row >> 9, t = row & 511;
    mask[t * 64 + b] = (bal != 0ull) ? 1 : 0;
  }
}

// ---------------- fused sequential scan, split-f16 (fp32-grade), fp32 out ----------------
// SENTINEL-PACKET handoff: the handshake word IS one of the data packets.
//  - Packets: 8B {hi-f16, lo-f16, tag(ti+1)<<32}, relaxed agent atomics; 8B
//    atomicity => tag can never tear from payload.
//  - Writer: phase D stores its 2 packets per thread. NOTHING ELSE -- no
//    drain, no flag, no publish barrier. Writer-side chain cost is zero; it
//    flows straight into the next step's phase A.
//  - Reader: polls the partner block's packet 0 (the sentinel) -- all 32
//    lanes of a partner group poll the SAME 8B address, so the poll
//    broadcast-coalesces to one line per partner per round (exactly r0's
//    proven-cheap spin economics; none of r1/r3/r4's bulk-poll congestion).
//    Sentinel fresh => one-shot 16-packet load, per-packet tag validation,
//    straggler-only retry with backoff.
//  - Why this avoids r6's staleness storm: r6's flag was a SEPARATE 4B store
//    that commits on its own path and can beat the 512-packet burst by a full
//    RT. The sentinel is issued IN the same burst as its siblings (<=200cy
//    issue skew); the reader observes it >=1 poll RT (~600-900cy) after its
//    commit, by which time the siblings are committed. Tags remain the net.
// Overwrite safety (flag-free tag induction; field-validated r3/r6): I
// overwrite slot ti&1 at D(ti+2) only after my B(ti+2) validated every
// partner's tags >= ti+2 in slot (ti+1)&1, which each partner stores only
// after its B2(ti+1) barrier drained its reads of my slot-ti&1 data. A polled
// slot holds tag ti (fresh) or <ti (stale), never ahead (slot parity).
// Cross-step LDS hazards ordered by B2(ti+1)/B3 (2-barrier structure passed
// in r4/r5/r6/r7).
__global__ __launch_bounds__(256, 1) void k_scan(const float* __restrict__ Wk_f,
                                                 const float* __restrict__ Wr_f,
                                                 const float* __restrict__ b_f,
                                                 const float* __restrict__ Wk_b,
                                                 const float* __restrict__ Wr_b,
                                                 const float* __restrict__ b_b,
                                                 const float* __restrict__ x,
                                                 const unsigned char* __restrict__ mask,
                                                 u64* __restrict__ hx64,
                                                 float* __restrict__ out) {
  __shared__ u16 hhi[16][264], hlo[16][264];       // f16 bits, full 256 units
  __shared__ u16 xhi[2][16][264], xlo[2][16][264]; // f16 x tile, double-buffered
  __shared__ float zb[4][16][34];                  // [gate][row][unitcol+pad]

  int bid = blockIdx.x;
  int sg = bid & 7, q8 = bid >> 3;
  int d = sg >> 2, g = sg & 3;
  int tid = threadIdx.x;
  int w = tid >> 6, l = tid & 63;
  int p = w >> 1, sl = w & 1;
  int lg = l >> 4, li = l & 15;
  const float* Wk = d ? Wk_b : Wk_f;
  const float* Wr = d ? Wr_b : Wr_f;
  const float* bias = d ? b_b : b_f;

  int ncol0 = 256 * (2 * p) + 32 * q8 + 16 * sl + li;  // gate 2p column
  int ncol1 = ncol0 + 256;                             // gate 2p+1

  // Register-resident split weight B-fragments (m92-verified addressing).
  half8 wkh[2][8], wkl[2][8], wrh[2][8], wrl[2][8];
#pragma unroll
  for (int kk = 0; kk < 8; ++kk) {
#pragma unroll
    for (int jj = 0; jj < 8; ++jj) {
      int k = 32 * kk + 8 * lg + jj;
      _Float16 hi, lo;
      split2(Wk[(size_t)k * 1024 + ncol0], hi, lo); wkh[0][kk][jj] = hi; wkl[0][kk][jj] = lo;
      split2(Wk[(size_t)k * 1024 + ncol1], hi, lo); wkh[1][kk][jj] = hi; wkl[1][kk][jj] = lo;
      split2(Wr[(size_t)k * 1024 + ncol0], hi, lo); wrh[0][kk][jj] = hi; wrl[0][kk][jj] = lo;
      split2(Wr[(size_t)k * 1024 + ncol1], hi, lo); wrh[1][kk][jj] = hi; wrl[1][kk][jj] = lo;
    }
  }
  float bs0 = bias[ncol0], bs1 = bias[ncol1];

  for (int i = tid; i < 16 * 264; i += 256) { ((u16*)hhi)[i] = 0; ((u16*)hlo)[i] = 0; }
  float cst[2] = {0.f, 0.f}, hst[2] = {0.f, 0.f};

  // x staging: thread covers row sr, 16 cols at c0 of the 16x256 fp32 tile
  int sr = tid >> 4, c0 = (tid & 15) * 16;
  const float* xrow = x + ((size_t)(16 * g + sr) * 512) * 256 + c0;
  {
    int t0 = d ? 511 : 0;
    const float4v* xp = (const float4v*)(xrow + (size_t)t0 * 256);
    float va[16];
    *(float4v*)&va[0] = xp[0]; *(float4v*)&va[4] = xp[1];
    *(float4v*)&va[8] = xp[2]; *(float4v*)&va[12] = xp[3];
    half8 h0, h1, l0, l1;
#pragma unroll
    for (int j = 0; j < 8; ++j) {
      _Float16 hi, lo;
      split2(va[j], hi, lo);     h0[j] = hi; l0[j] = lo;
      split2(va[8 + j], hi, lo); h1[j] = hi; l1[j] = lo;
    }
    *(half8*)(void*)&xhi[0][sr][c0] = h0; *(half8*)(void*)&xhi[0][sr][c0 + 8] = h1;
    *(half8*)(void*)&xlo[0][sr][c0] = l0; *(half8*)(void*)&xlo[0][sr][c0 + 8] = l1;
  }
  __syncthreads();

  for (int ti = 0; ti < 512; ++ti) {
    int t = d ? (511 - ti) : ti;
    int buf = ti & 1;

    // issue next step's x loads + this step's mask loads early
    float4v xa0, xa1, xa2, xa3;
    if (ti < 511) {
      int tn = d ? (510 - ti) : (ti + 1);
      const float4v* xp = (const float4v*)(xrow + (size_t)tn * 256);
      xa0 = xp[0]; xa1 = xp[1]; xa2 = xp[2]; xa3 = xp[3];
    }
    int m0 = 2 * (tid >> 5);
    int mk0 = mask[t * 64 + 16 * g + m0];
    int mk1 = mask[t * 64 + 16 * g + m0 + 1];

    // phase A: z = b + x@Wk (split); covers partner publish->visibility window
    float4v zm0 = {bs0, bs0, bs0, bs0}, zm1 = {bs1, bs1, bs1, bs1};
    float4v zc0 = {0.f, 0.f, 0.f, 0.f}, zc1 = {0.f, 0.f, 0.f, 0.f};
#pragma unroll
    for (int kk = 0; kk < 8; ++kk) {
      half8 axh = *(const half8*)(const void*)&xhi[buf][li][32 * kk + 8 * lg];
      half8 axl = *(const half8*)(const void*)&xlo[buf][li][32 * kk + 8 * lg];
      zm0 = __builtin_amdgcn_mfma_f32_16x16x32_f16(axh, wkh[0][kk], zm0, 0, 0, 0);
      zc0 = __builtin_amdgcn_mfma_f32_16x16x32_f16(axh, wkl[0][kk], zc0, 0, 0, 0);
      zc0 = __builtin_amdgcn_mfma_f32_16x16x32_f16(axl, wkh[0][kk], zc0, 0, 0, 0);
      zm1 = __builtin_amdgcn_mfma_f32_16x16x32_f16(axh, wkh[1][kk], zm1, 0, 0, 0);
      zc1 = __builtin_amdgcn_mfma_f32_16x16x32_f16(axh, wkl[1][kk], zc1, 0, 0, 0);
      zc1 = __builtin_amdgcn_mfma_f32_16x16x32_f16(axl, wkh[1][kk], zc1, 0, 0, 0);
    }

    // phase B: sentinel spin (1 coalesced line per partner, r0 economics) ->
    // one-shot 16-packet load -> tag validation -> straggler retry w/ backoff.
    if (ti > 0 && tid < 224) {
      int pi = tid >> 5, rb = tid & 31;
      int qq = (q8 + 1 + pi) & 7;
      int rm = rb >> 1, cc = 16 * (rb & 1);
      int slot2 = (ti - 1) & 1;
      size_t pbase = (((size_t)(slot2 * 2 + d) * 4 + g) * 8 + qq) * 512;  // 16*32 packets
      const u64* sent = hx64 + pbase;  // packet (row0,col0) = the sentinel
      while ((u32)(__hip_atomic_load(sent, __ATOMIC_RELAXED, __HIP_MEMORY_SCOPE_AGENT) >> 32) < (u32)ti)
        __builtin_amdgcn_s_sleep(1);
      const u64* hp8 = hx64 + pbase + rm * 32 + cc;
      u64 v[16];
#pragma unroll
      for (int j = 0; j < 16; ++j)
        v[j] = __hip_atomic_load(hp8 + j, __ATOMIC_RELAXED, __HIP_MEMORY_SCOPE_AGENT);
      // validate: sentinel was issued in the same burst as these; our load
      // arrived >=1 RT after its commit => stragglers rare; retry them only.
      for (;;) {
        u32 bad = 0;
#pragma unroll
        for (int j = 0; j < 16; ++j)
          if ((u32)(v[j] >> 32) < (u32)ti) bad |= (1u << j);
        if (bad == 0) break;
        __builtin_amdgcn_s_sleep(1);
#pragma unroll
        for (int j = 0; j < 16; ++j)
          if (bad & (1u << j))
            v[j] = __hip_atomic_load(hp8 + j, __ATOMIC_RELAXED, __HIP_MEMORY_SCOPE_AGENT);
      }
      // unpack: payload is the writer's split pair (no reader-side split2)
      ushort8 h0, h1, l0, l1;
#pragma unroll
      for (int j = 0; j < 8; ++j) {
        u32 d0 = (u32)v[j], d1 = (u32)v[8 + j];
        h0[j] = (u16)(d0 & 0xffffu); l0[j] = (u16)(d0 >> 16);
        h1[j] = (u16)(d1 & 0xffffu); l1[j] = (u16)(d1 >> 16);
      }
      *(ushort8*)(void*)&hhi[rm][32 * qq + cc]     = h0;
      *(ushort8*)(void*)&hhi[rm][32 * qq + cc + 8] = h1;
      *(ushort8*)(void*)&hlo[rm][32 * qq + cc]     = l0;
      *(ushort8*)(void*)&hlo[rm][32 * qq + cc + 8] = l1;
    }
    __syncthreads();  // B2: hhi/hlo complete (drains phase-B loads)

    // phase C: z += h @ Wr (split)
#pragma unroll
    for (int kk = 0; kk < 8; ++kk) {
      half8 ahh = *(const half8*)(const void*)&hhi[li][32 * kk + 8 * lg];
      half8 ahl = *(const half8*)(const void*)&hlo[li][32 * kk + 8 * lg];
      zm0 = __builtin_amdgcn_mfma_f32_16x16x32_f16(ahh, wrh[0][kk], zm0, 0, 0, 0);
      zc0 = __builtin_amdgcn_mfma_f32_16x16x32_f16(ahh, wrl[0][kk], zc0, 0, 0, 0);
      zc0 = __builtin_amdgcn_mfma_f32_16x16x32_f16(ahl, wrh[0][kk], zc0, 0, 0, 0);
      zm1 = __builtin_amdgcn_mfma_f32_16x16x32_f16(ahh, wrh[1][kk], zm1, 0, 0, 0);
      zc1 = __builtin_amdgcn_mfma_f32_16x16x32_f16(ahh, wrl[1][kk], zc1, 0, 0, 0);
      zc1 = __builtin_amdgcn_mfma_f32_16x16x32_f16(ahl, wrh[1][kk], zc1, 0, 0, 0);
    }
#pragma unroll
    for (int rr = 0; rr < 4; ++rr) {
      zb[2 * p][4 * lg + rr][16 * sl + li] = clamp30(zm0[rr] + zc0[rr] * LO_ISCALE);
      zb[2 * p + 1][4 * lg + rr][16 * sl + li] = clamp30(zm1[rr] + zc1[rr] * LO_ISCALE);
    }

    // stage x(t+1) into the other buffer (read next iter, after B3)
    if (ti < 511) {
      float va[16];
      *(float4v*)&va[0] = xa0; *(float4v*)&va[4] = xa1;
      *(float4v*)&va[8] = xa2; *(float4v*)&va[12] = xa3;
      half8 h0, h1, l0, l1;
#pragma unroll
      for (int j = 0; j < 8; ++j) {
        _Float16 hi, lo;
        split2(va[j], hi, lo);     h0[j] = hi; l0[j] = lo;
        split2(va[8 + j], hi, lo); h1[j] = hi; l1[j] = lo;
      }
      *(half8*)(void*)&xhi[buf ^ 1][sr][c0] = h0;
      *(half8*)(void*)&xhi[buf ^ 1][sr][c0 + 8] = h1;
      *(half8*)(void*)&xlo[buf ^ 1][sr][c0] = l0;
      *(half8*)(void*)&xlo[buf ^ 1][sr][c0 + 8] = l1;
    }
    __syncthreads();  // B3: zb + x stage ready

    // phase D: state update — thread owns unit-col uo, rows m0,m0+1.
    // Publish = the packet stores themselves. No drain, no flag, no B4.
    int uo = tid & 31;
    int slot = ti & 1;
    u64 tagw = ((u64)(u32)(ti + 1)) << 32;
#pragma unroll
    for (int e2 = 0; e2 < 2; ++e2) {
      int m = m0 + e2;
      float zi = zb[0][m][uo];
      float zf = zb[1][m][uo];
      float zg = zb[2][m][uo];
      float zo = zb[3][m][uo];
      float gi = ftanh(zi), gf = ftanh(zf), gg = ftanh(zg), go = ftanh(zo);
      float cn = gf * cst[e2] + gi * gg;
      float hn = go * ftanh(cn);
      bool mk = (e2 ? mk1 : mk0) != 0;
      cst[e2] = mk ? cn : cst[e2];
      hst[e2] = mk ? hn : hst[e2];
      float hv = hst[e2];
      _Float16 hi, lo; split2(hv, hi, lo);
      hhi[m][32 * q8 + uo] = h2u(hi);
      hlo[m][32 * q8 + uo] = h2u(lo);
      u64 pk = (u64)((u32)h2u(hi) | ((u32)h2u(lo) << 16)) | tagw;
      __hip_atomic_store(
          hx64 + ((((size_t)(slot * 2 + d) * 4 + g) * 8 + q8) * 16 + m) * 32 + uo,
          pk, __ATOMIC_RELAXED, __HIP_MEMORY_SCOPE_AGENT);
    }
    // out stores last (off the handoff chain entirely)
#pragma unroll
    for (int e2 = 0; e2 < 2; ++e2) {
      int b = 16 * g + m0 + e2;
      out[((size_t)b * 512 + t) * 512 + 256 * d + 32 * q8 + uo] = hst[e2];
    }
  }

  // state_h (fp32)
  {
    int uo = tid & 31;
    int m0 = 2 * (tid >> 5);
#pragma unroll
    for (int e2 = 0; e2 < 2; ++e2) {
      int b = 16 * g + m0 + e2;
      out[(size_t)16777216 + (size_t)b * 512 + 256 * d + 32 * q8 + uo] = hst[e2];
    }
  }
}

extern "C" void kernel_launch(void* const* d_in, const int* in_sizes, int n_in,
                              void* d_out, int out_size, void* d_ws, size_t ws_size,
                              hipStream_t stream) {
  const float* x    = (const float*)d_in[0];
  const float* Wk_f = (const float*)d_in[1];
  const float* Wr_f = (const float*)d_in[2];
  const float* b_f  = (const float*)d_in[3];
  const float* Wk_b = (const float*)d_in[4];
  const float* Wr_b = (const float*)d_in[5];
  const float* b_b  = (const float*)d_in[6];
  char* ws = (char*)d_ws;
  u64* hx64  = (u64*)(ws + OFF_HX);
  unsigned char* maskp = (unsigned char*)(ws + OFF_MASK);
  float* out = (float*)d_out;

  k_mask<<<8192, 256, 0, stream>>>(x, maskp, hx64);
  k_scan<<<64, 256, 0, stream>>>(Wk_f, Wr_f, b_f, Wk_b, Wr_b, b_b, x, maskp, hx64, out);
}